// Round 4
// baseline (120.306 us; speedup 1.0000x reference)
//
#include <hip/hip_runtime.h>
#include <stdint.h>

typedef __attribute__((ext_vector_type(8))) short short8;
typedef __attribute__((ext_vector_type(4))) float f32x4;
typedef unsigned short ushort_t;

// fp32 -> bf16 round-to-nearest-even
__device__ __forceinline__ ushort_t f2bf(float f) {
  uint32_t u = __float_as_uint(f);
  u += 0x7fffu + ((u >> 16) & 1u);
  return (ushort_t)(u >> 16);
}

__device__ __forceinline__ uint2 pack4(float4 v) {
  return make_uint2((uint32_t)f2bf(v.x) | ((uint32_t)f2bf(v.y) << 16),
                    (uint32_t)f2bf(v.z) | ((uint32_t)f2bf(v.w) << 16));
}

// async global->LDS, 16B per lane; LDS dest = wave-uniform base + lane*16
__device__ __forceinline__ void load_lds16(const ushort_t* g, ushort_t* l) {
  __builtin_amdgcn_global_load_lds(
      (const __attribute__((address_space(1))) uint32_t*)g,
      (__attribute__((address_space(3))) uint32_t*)l, 16, 0, 0);
}

// --- K1 (fused): blocks 0..511  -> HLt[b][o][m] = sum_i W[o,i]H[b,m,i] + b[o]
//                 blocks 512..1023 -> deg rowsums of (A+I) -> dis, dis*mask
__global__ __launch_bounds__(256) void k_fused1(
    const float* __restrict__ W,      // [256][256] fp32
    const float* __restrict__ H,      // [32][512][256] fp32
    const float* __restrict__ bias,   // [256]
    const float* __restrict__ mask,   // [32*512]
    const float4* __restrict__ A4,    // [32*512*128] fp32 as float4
    float* __restrict__ dis,          // [32*512] out
    float* __restrict__ dmask,        // [32*512] out (dis*mask)
    ushort_t* __restrict__ HLt) {     // [32][256][512] bf16 out
  const int bid = blockIdx.x;
  const int tid = threadIdx.x, lane = tid & 63, wv = tid >> 6;

  if (bid >= 512) {  // ---- rowsum job: 32 rows per block, 8 per wave ----
    const int r = bid - 512;
    const int row0 = r * 32 + wv * 8;
#pragma unroll
    for (int i = 0; i < 8; ++i) {
      const int row = row0 + i;
      const float4* src = A4 + (size_t)row * 128;
      float4 a = src[lane], b = src[64 + lane];
      float s = (a.x + a.y) + (a.z + a.w) + (b.x + b.y) + (b.z + b.w);
#pragma unroll
      for (int off = 32; off > 0; off >>= 1) s += __shfl_xor(s, off, 64);
      if (lane == 0) {
        float d = rsqrtf(s + 1.0f + 1e-8f);  // +1: identity fold
        dis[row] = d;
        dmask[row] = d * mask[row];
      }
    }
    return;
  }

  // ---- GEMM job: tile 64(o) x 128(m), K=256, BK=32, fp32 inline convert ----
  __shared__ ushort_t As[2][64 * 32];   // W rows  (o x k)
  __shared__ ushort_t Bs[2][128 * 32];  // H rows  (m x k)
  const int yo = bid >> 7;    // o-tile 0..3
  const int rr = bid & 127;
  const int batch = rr >> 2;  // 0..31
  const int xm = rr & 3;      // m-tile 0..3
  const int ot0 = yo * 64, mt0 = xm * 128;
  const int wo = wv & 1;    // o half (2 x 32)
  const int wmh = wv >> 1;  // m half (2 x 64)
  const int lr = lane & 15, q = lane >> 4;
  const float* Hb = H + (size_t)batch * 512 * 256;

  const int a_r = tid >> 2, a_kc = (tid & 3) * 8;   // W: 64 rows x 4 chunks
  const int b_r = tid >> 1, b_kc = (tid & 1) * 16;  // H: 128 rows x 2 chunks

  f32x4 acc[2][4];
#pragma unroll
  for (int i = 0; i < 2; ++i)
#pragma unroll
    for (int j = 0; j < 4; ++j) acc[i][j] = {0.f, 0.f, 0.f, 0.f};

  float4 ra[2], rb[4];
  auto gload = [&](int k0) {
    const float* wp = W + (size_t)(ot0 + a_r) * 256 + k0 + a_kc;
    ra[0] = *(const float4*)wp;
    ra[1] = *(const float4*)(wp + 4);
    const float* hp = Hb + (size_t)(mt0 + b_r) * 256 + k0 + b_kc;
#pragma unroll
    for (int j = 0; j < 4; ++j) rb[j] = *(const float4*)(hp + 4 * j);
  };
  auto stash = [&](int p) {
    uint2 a0 = pack4(ra[0]), a1 = pack4(ra[1]);
    *(uint4*)&As[p][a_r * 32 + a_kc] = make_uint4(a0.x, a0.y, a1.x, a1.y);
    uint2 b0 = pack4(rb[0]), b1 = pack4(rb[1]);
    uint2 b2 = pack4(rb[2]), b3 = pack4(rb[3]);
    *(uint4*)&Bs[p][b_r * 32 + b_kc] = make_uint4(b0.x, b0.y, b1.x, b1.y);
    *(uint4*)&Bs[p][b_r * 32 + b_kc + 8] = make_uint4(b2.x, b2.y, b3.x, b3.y);
  };
  auto compute = [&](int p) {
    short8 af[2], bfr[4];
#pragma unroll
    for (int mt = 0; mt < 2; ++mt)
      af[mt] = *(const short8*)&As[p][(wo * 32 + mt * 16 + lr) * 32 + q * 8];
#pragma unroll
    for (int nt = 0; nt < 4; ++nt)
      bfr[nt] = *(const short8*)&Bs[p][(wmh * 64 + nt * 16 + lr) * 32 + q * 8];
#pragma unroll
    for (int mt = 0; mt < 2; ++mt)
#pragma unroll
      for (int nt = 0; nt < 4; ++nt)
        acc[mt][nt] = __builtin_amdgcn_mfma_f32_16x16x32_bf16(
            af[mt], bfr[nt], acc[mt][nt], 0, 0, 0);
  };

  gload(0);
#pragma unroll
  for (int it = 0; it < 8; ++it) {
    stash(it & 1);
    __syncthreads();
    if (it + 1 < 8) gload((it + 1) * 32);
    compute(it & 1);
  }

#pragma unroll
  for (int mt = 0; mt < 2; ++mt) {
    const int ob = ot0 + wo * 32 + mt * 16 + q * 4;
    float bs[4];
#pragma unroll
    for (int r = 0; r < 4; ++r) bs[r] = bias[ob + r];
#pragma unroll
    for (int nt = 0; nt < 4; ++nt) {
      const int m = mt0 + wmh * 64 + nt * 16 + lr;
      ushort_t* dstp = HLt + ((size_t)batch * 256 + ob) * 512 + m;
#pragma unroll
      for (int r = 0; r < 4; ++r)
        dstp[(size_t)r * 512] = f2bf(acc[mt][nt][r] + bs[r]);
    }
  }
}

// --- K2: out[b][n][o] = relu( dmask[b,n] * sum_m (A+I)[n,m]*dis[m]*HLt[o,m] )
// tile 64(n) x 128(o), K=512, BK=32. A read fp32; identity + dis[m] column
// scale folded into the bf16 staging. grid 512: bid = yo*256 + batch*8 + xn
// (the 2 o-blocks sharing A rows land on one XCD).
__global__ __launch_bounds__(256) void k_gemm_out(
    const float* __restrict__ A,       // [32][512][512] fp32
    const ushort_t* __restrict__ HLt,  // [32][256][512] bf16
    const float* __restrict__ dis,     // [32*512]
    const float* __restrict__ dmask,   // [32*512]
    float* __restrict__ out) {         // [32][512][256] fp32
  __shared__ ushort_t As[2][64 * 32];   // Ahat rows (n x k), dis-scaled
  __shared__ ushort_t Bs[2][128 * 32];  // HLt rows  (o x k=m)
  const int bid = blockIdx.x;
  const int yo = bid >> 8;     // o-tile 0..1
  const int rem = bid & 255;
  const int batch = rem >> 3;  // 0..31
  const int xn = rem & 7;      // n-tile 0..7
  const int nt0 = xn * 64, ot0 = yo * 128;
  const int tid = threadIdx.x, lane = tid & 63, wv = tid >> 6;
  const int wn2 = wv & 1;   // n half (2 x 32)
  const int wo2 = wv >> 1;  // o half (2 x 64)
  const int lr = lane & 15, q = lane >> 4;
  const int rstage = lane >> 2, koff = (lane & 3) * 8;
  const float* Ab = A + (size_t)batch * 512 * 512;
  const ushort_t* Gb = HLt + (size_t)batch * 256 * 512;

  const int a_r = tid >> 2, a_kc = (tid & 3) * 8;  // A: 64 rows x 4 chunks
  const int n_glob = nt0 + a_r;

  f32x4 acc[2][4];
#pragma unroll
  for (int i = 0; i < 2; ++i)
#pragma unroll
    for (int j = 0; j < 4; ++j) acc[i][j] = {0.f, 0.f, 0.f, 0.f};

  float4 ra[2], dv[2];
  auto gloadA = [&](int k0) {
    const float* ap = Ab + (size_t)n_glob * 512 + k0 + a_kc;
    ra[0] = *(const float4*)ap;
    ra[1] = *(const float4*)(ap + 4);
    dv[0] = *(const float4*)&dis[batch * 512 + k0 + a_kc];
    dv[1] = *(const float4*)&dis[batch * 512 + k0 + a_kc + 4];
  };
  auto stashA = [&](int k0, int p) {
    const int m0 = k0 + a_kc;  // identity fold, then dis[m] column scale
    ra[0].x = (ra[0].x + (float)(n_glob == m0)) * dv[0].x;
    ra[0].y = (ra[0].y + (float)(n_glob == m0 + 1)) * dv[0].y;
    ra[0].z = (ra[0].z + (float)(n_glob == m0 + 2)) * dv[0].z;
    ra[0].w = (ra[0].w + (float)(n_glob == m0 + 3)) * dv[0].w;
    ra[1].x = (ra[1].x + (float)(n_glob == m0 + 4)) * dv[1].x;
    ra[1].y = (ra[1].y + (float)(n_glob == m0 + 5)) * dv[1].y;
    ra[1].z = (ra[1].z + (float)(n_glob == m0 + 6)) * dv[1].z;
    ra[1].w = (ra[1].w + (float)(n_glob == m0 + 7)) * dv[1].w;
    uint2 p0 = pack4(ra[0]), p1 = pack4(ra[1]);
    *(uint4*)&As[p][a_r * 32 + a_kc] = make_uint4(p0.x, p0.y, p1.x, p1.y);
  };
  auto stageB = [&](int k0, int p) {
#pragma unroll
    for (int j = 0; j < 2; ++j) {
      const int c = wv * 2 + j;
      load_lds16(Gb + (size_t)(ot0 + c * 16 + rstage) * 512 + k0 + koff,
                 &Bs[p][c * 512]);
    }
  };
  auto compute = [&](int p) {
    short8 af[2], bfr[4];
#pragma unroll
    for (int mt = 0; mt < 2; ++mt)
      af[mt] = *(const short8*)&As[p][(wn2 * 32 + mt * 16 + lr) * 32 + q * 8];
#pragma unroll
    for (int nt = 0; nt < 4; ++nt)
      bfr[nt] = *(const short8*)&Bs[p][(wo2 * 64 + nt * 16 + lr) * 32 + q * 8];
#pragma unroll
    for (int mt = 0; mt < 2; ++mt)
#pragma unroll
      for (int nt = 0; nt < 4; ++nt)
        acc[mt][nt] = __builtin_amdgcn_mfma_f32_16x16x32_bf16(
            af[mt], bfr[nt], acc[mt][nt], 0, 0, 0);
  };

  gloadA(0);
  stageB(0, 0);
#pragma unroll
  for (int it = 0; it < 16; ++it) {
    stashA(it * 32, it & 1);
    __syncthreads();  // B(it) landed, A-stash(it) visible, buf !(it&1) free
    if (it + 1 < 16) {
      gloadA((it + 1) * 32);
      stageB((it + 1) * 32, (it + 1) & 1);
    }
    compute(it & 1);
  }

#pragma unroll
  for (int mt = 0; mt < 2; ++mt) {
    const int nb = nt0 + wn2 * 32 + mt * 16 + q * 4;
    float sc[4];
#pragma unroll
    for (int r = 0; r < 4; ++r) sc[r] = dmask[batch * 512 + nb + r];
#pragma unroll
    for (int nt = 0; nt < 4; ++nt) {
      const int o = ot0 + wo2 * 64 + nt * 16 + lr;
      float* dstp = out + ((size_t)(batch * 512 + nb)) * 256 + o;
#pragma unroll
      for (int r = 0; r < 4; ++r) {
        float v = acc[mt][nt][r] * sc[r];
        dstp[(size_t)r * 256] = v > 0.0f ? v : 0.0f;
      }
    }
  }
}

extern "C" void kernel_launch(void* const* d_in, const int* in_sizes, int n_in,
                              void* d_out, int out_size, void* d_ws,
                              size_t ws_size, hipStream_t stream) {
  const float* H = (const float*)d_in[0];     // [32][512][256]
  const float* A = (const float*)d_in[1];     // [32][512][512]
  const float* mask = (const float*)d_in[2];  // [32][512]
  const float* W = (const float*)d_in[3];     // [256][256]
  const float* b = (const float*)d_in[4];     // [256]
  float* out = (float*)d_out;                 // [32][512][256]

  char* ws = (char*)d_ws;
  ushort_t* HLt = (ushort_t*)ws;                  // 8 MiB
  float* dis = (float*)(ws + 8388608);            // 64 KiB
  float* dmask = (float*)(ws + 8388608 + 65536);  // 64 KiB

  // 1) fused: HLt = (W @ H^T + b) [bf16, transposed]  ||  deg -> dis, dmask
  k_fused1<<<1024, 256, 0, stream>>>(W, H, b, mask, (const float4*)A, dis,
                                     dmask, HLt);
  // 2) out = relu(dmask[n] * sum_m (A+I)[n,m]*dis[m] * HLt[o,m])
  k_gemm_out<<<512, 256, 0, stream>>>(A, HLt, dis, dmask, out);
}